// Round 2
// baseline (265.640 us; speedup 1.0000x reference)
//
#include <hip/hip_runtime.h>
#include <stdint.h>

#define DEV __device__ __forceinline__

typedef unsigned short u16;
typedef u16   u16x8 __attribute__((ext_vector_type(8)));
typedef u16   u16x4 __attribute__((ext_vector_type(4)));
typedef __bf16 bf16x8v __attribute__((ext_vector_type(8)));
typedef float f32x4 __attribute__((ext_vector_type(4)));

// problem constants
constexpr int C192 = 192;
constexpr int NWIN = 81;          // 9x9 windows per batch
constexpr int BN   = 4 * NWIN;    // 324 total windows
constexpr float EPS = 1e-5f;
constexpr float SCALE = 0.07216878364870322f; // 192^-0.5 (QK_DIM^-0.5)

DEV u16 f2bf(float f) {            // fp32 -> bf16 RNE
    unsigned u = __builtin_bit_cast(unsigned, f);
    u += 0x7fffu + ((u >> 16) & 1u);
    return (u16)(u >> 16);
}

DEV f32x4 mfma16(bf16x8v a, bf16x8v b, f32x4 c) {
    return __builtin_amdgcn_mfma_f32_16x16x32_bf16(a, b, c, 0, 0, 0);
}

// ---------------- kernel 0: convert Wq|Wk|Wv fp32 -> bf16 (contiguous in ws)
__global__ void wconv(const float* __restrict__ wq, const float* __restrict__ wk,
                      const float* __restrict__ wv, u16* __restrict__ dst) {
    int idx = blockIdx.x * 256 + threadIdx.x;       // 3*36864 exact
    const float* src = (idx < 36864) ? wq : (idx < 73728 ? wk : wv);
    int r = (idx < 36864) ? idx : (idx < 73728 ? idx - 36864 : idx - 73728);
    dst[idx] = f2bf(src[r]);
}

// ---------------- kernel 1: per (window, s-half): LN + Q,K,V^T projections
// block: 256 threads (4 waves). LDS: lx[128][200] bf16 + stats.
__launch_bounds__(256, 1)
__global__ void proj_kernel(const float* __restrict__ x, const u16* __restrict__ wbf,
                            const float* __restrict__ gamma, const float* __restrict__ beta,
                            u16* __restrict__ q_g, u16* __restrict__ k_g, u16* __restrict__ vT_g) {
    __shared__ u16 lx[128 * 200];           // [token][c], stride 200 (400B: 16B-mult, bank-spread)
    __shared__ float part1[2][64][4], part2[2][64][4];
    __shared__ float mu_s[128], rs_s[128];

    const int tid = threadIdx.x;
    const int win = blockIdx.x >> 1, half = blockIdx.x & 1;
    const int b = win / NWIN, wi = win % NWIN;
    const int t0 = 14 * (wi / 9), l0 = 14 * (wi % 9);

    // ---- pass 1: per-token LN stats (coalesced float2 loads, l0 always even)
    const int j2 = tid & 7, il = (tid >> 3) & 7, cg = tid >> 6;
    const float* xbase = x + ((long)(b * C192) * 128 + (t0 + 8 * half + il)) * 128 + l0 + 2 * j2;
    float s1a = 0, s2a = 0, s1b = 0, s2b = 0;
    for (int c = cg; c < C192; c += 4) {
        float2 v = *(const float2*)(xbase + (long)c * 16384);
        s1a += v.x; s2a += v.x * v.x; s1b += v.y; s2b += v.y * v.y;
    }
    const int tp = il * 8 + j2;
    part1[0][tp][cg] = s1a; part2[0][tp][cg] = s2a;
    part1[1][tp][cg] = s1b; part2[1][tp][cg] = s2b;
    __syncthreads();
    if (tid < 128) {
        int e = tid & 1, tpp = tid >> 1;
        float s1 = part1[e][tpp][0] + part1[e][tpp][1] + part1[e][tpp][2] + part1[e][tpp][3];
        float s2 = part2[e][tpp][0] + part2[e][tpp][1] + part2[e][tpp][2] + part2[e][tpp][3];
        float mu = s1 * (1.0f / 192.0f);
        float var = s2 * (1.0f / 192.0f) - mu * mu;
        mu_s[tid] = mu; rs_s[tid] = rsqrtf(var + EPS);
    }
    __syncthreads();

    // ---- pass 2: reload (L2-hot), normalize, store bf16 to LDS (single rounding)
    const int tka = 16 * il + 2 * j2, tkb = tka + 1;
    const float mua = mu_s[tka], rsa = rs_s[tka];
    const float mub = mu_s[tkb], rsb = rs_s[tkb];
    for (int c = cg; c < C192; c += 4) {
        float2 v = *(const float2*)(xbase + (long)c * 16384);
        float g = gamma[c], be = beta[c];
        lx[tka * 200 + c] = f2bf((v.x - mua) * rsa * g + be);
        lx[tkb * 200 + c] = f2bf((v.y - mub) * rsb * g + be);
    }
    __syncthreads();

    // ---- MFMA projections
    const int wv_ = tid >> 6, lane = tid & 63;
    const int l15 = lane & 15, g4 = lane >> 4;
    const u16* wq_b = wbf;
    const u16* wk_b = wbf + 36864;
    const u16* wv_b = wbf + 73728;
    const long sbase = (long)win * 256 + 128 * half;

    // Q, K : [s][o] = lx . W^T   (A = lx rows, B = W rows [o][c])
    for (int qk = 0; qk < 2; ++qk) {
        const u16* wsrc = qk ? wk_b : wq_b;
        u16* dst = qk ? k_g : q_g;
        for (int ntp = 0; ntp < 6; ++ntp) {
            f32x4 acc[2][2] = {};
            #pragma unroll
            for (int ks = 0; ks < 6; ++ks) {
                bf16x8v a0 = *(const bf16x8v*)&lx[(16 * (2 * wv_ + 0) + l15) * 200 + 32 * ks + 8 * g4];
                bf16x8v a1 = *(const bf16x8v*)&lx[(16 * (2 * wv_ + 1) + l15) * 200 + 32 * ks + 8 * g4];
                bf16x8v b0 = *(const bf16x8v*)&wsrc[(16 * (2 * ntp + 0) + l15) * 192 + 32 * ks + 8 * g4];
                bf16x8v b1 = *(const bf16x8v*)&wsrc[(16 * (2 * ntp + 1) + l15) * 192 + 32 * ks + 8 * g4];
                acc[0][0] = mfma16(a0, b0, acc[0][0]); acc[0][1] = mfma16(a0, b1, acc[0][1]);
                acc[1][0] = mfma16(a1, b0, acc[1][0]); acc[1][1] = mfma16(a1, b1, acc[1][1]);
            }
            #pragma unroll
            for (int mi = 0; mi < 2; ++mi)
                #pragma unroll
                for (int ni = 0; ni < 2; ++ni)
                    #pragma unroll
                    for (int r = 0; r < 4; ++r) {
                        long s = sbase + 16 * (2 * wv_ + mi) + 4 * g4 + r;
                        int o = 16 * (2 * ntp + ni) + l15;
                        dst[s * 192 + o] = f2bf(acc[mi][ni][r]);
                    }
        }
    }
    // V^T : [o][s] = W . lx^T   (A = Wv rows [o][c], B = lx rows [s][c])
    for (int mtl = 0; mtl < 3; ++mtl) {
        int mt = 3 * wv_ + mtl;
        for (int ntp = 0; ntp < 4; ++ntp) {
            f32x4 acc[2] = {};
            #pragma unroll
            for (int ks = 0; ks < 6; ++ks) {
                bf16x8v a  = *(const bf16x8v*)&wv_b[(16 * mt + l15) * 192 + 32 * ks + 8 * g4];
                bf16x8v b0 = *(const bf16x8v*)&lx[(16 * (2 * ntp + 0) + l15) * 200 + 32 * ks + 8 * g4];
                bf16x8v b1 = *(const bf16x8v*)&lx[(16 * (2 * ntp + 1) + l15) * 200 + 32 * ks + 8 * g4];
                acc[0] = mfma16(a, b0, acc[0]); acc[1] = mfma16(a, b1, acc[1]);
            }
            #pragma unroll
            for (int ni = 0; ni < 2; ++ni)
                #pragma unroll
                for (int r = 0; r < 4; ++r) {
                    int o = 16 * mt + 4 * g4 + r;
                    long s = 128 * half + 16 * (2 * ntp + ni) + l15;
                    vT_g[((long)win * 192 + o) * 256 + s] = f2bf(acc[ni][r]);
                }
        }
    }
}

// ---------------- kernel 2: per (window, head) attention. 512 threads (8 waves).
// LDS: Q[256][40] + K[256][40] (P[256][72] overlays Q+K) + VT[32][264]
__launch_bounds__(512, 2)
__global__ void attn_kernel(const u16* __restrict__ q_g, const u16* __restrict__ k_g,
                            const u16* __restrict__ vT_g, float* __restrict__ out_win) {
    __shared__ u16 smem[28928];
    u16* Qs = smem;            // [256][40]
    u16* Ks = smem + 10240;    // [256][40]
    u16* Ps = smem;            // overlay [256][72]
    u16* Vs = smem + 20480;    // [32][264]

    const int tid = threadIdx.x;
    const int win = blockIdx.x / 6, h = blockIdx.x % 6;

    { // stage Q,K head-slices [256][32] and V^T slice [32][256] into LDS
        int c4 = tid & 3, srow = tid >> 2;
        long base = ((long)win * 256) * 192 + 32 * h + 8 * c4;
        #pragma unroll
        for (int it = 0; it < 2; ++it) {
            int s = srow + 128 * it;
            *(u16x8*)&Qs[s * 40 + 8 * c4] = *(const u16x8*)&q_g[base + (long)s * 192];
            *(u16x8*)&Ks[s * 40 + 8 * c4] = *(const u16x8*)&k_g[base + (long)s * 192];
        }
        int cv = tid & 15, rv = tid >> 4;
        long vbase = ((long)win * 192 + 32 * h + rv) * 256;
        #pragma unroll
        for (int it = 0; it < 2; ++it) {
            int cc = 8 * cv + 128 * it;
            *(u16x8*)&Vs[rv * 264 + cc] = *(const u16x8*)&vT_g[vbase + cc];
        }
    }
    __syncthreads();

    const int lane = tid & 63, wv_ = tid >> 6;
    const int l15 = lane & 15, g4 = lane >> 4;

    // scoresT[key][q] = K . Q^T ; wave owns q-tiles {2wv_, 2wv_+1}
    f32x4 sc[16][2];
    {
        bf16x8v bq0 = *(const bf16x8v*)&Qs[(16 * (2 * wv_ + 0) + l15) * 40 + 8 * g4];
        bf16x8v bq1 = *(const bf16x8v*)&Qs[(16 * (2 * wv_ + 1) + l15) * 40 + 8 * g4];
        f32x4 z = {0.f, 0.f, 0.f, 0.f};
        #pragma unroll
        for (int mt = 0; mt < 16; ++mt) {
            bf16x8v a = *(const bf16x8v*)&Ks[(16 * mt + l15) * 40 + 8 * g4];
            sc[mt][0] = mfma16(a, bq0, z);
            sc[mt][1] = mfma16(a, bq1, z);
        }
    }

    // softmax over keys (column of scoresT): lane-local 64 vals + xor16 + xor32
    float rden[2];
    #pragma unroll
    for (int nq = 0; nq < 2; ++nq) {
        float mx = -1e30f;
        #pragma unroll
        for (int mt = 0; mt < 16; ++mt)
            #pragma unroll
            for (int r = 0; r < 4; ++r) mx = fmaxf(mx, sc[mt][nq][r]);
        mx = fmaxf(mx, __shfl_xor(mx, 16, 64));
        mx = fmaxf(mx, __shfl_xor(mx, 32, 64));
        float sum = 0.f;
        #pragma unroll
        for (int mt = 0; mt < 16; ++mt)
            #pragma unroll
            for (int r = 0; r < 4; ++r) {
                float p = __expf((sc[mt][nq][r] - mx) * SCALE);
                sc[mt][nq][r] = p; sum += p;
            }
        sum += __shfl_xor(sum, 16, 64);
        sum += __shfl_xor(sum, 32, 64);
        rden[nq] = 1.0f / sum;
    }

    // PV: outT[dv][q] = V^T . P^T, P staged per 64-key chunk in LDS (overlays Q/K)
    f32x4 oacc[2][2] = {};
    #pragma unroll
    for (int kc = 0; kc < 4; ++kc) {
        __syncthreads();   // prev readers of Ps region (or Q/K at kc=0) done
        #pragma unroll
        for (int mtl = 0; mtl < 4; ++mtl) {
            int mt = 4 * kc + mtl;
            #pragma unroll
            for (int nq = 0; nq < 2; ++nq) {
                int q = 16 * (2 * wv_ + nq) + l15;
                u16x4 pk = { f2bf(sc[mt][nq][0]), f2bf(sc[mt][nq][1]),
                             f2bf(sc[mt][nq][2]), f2bf(sc[mt][nq][3]) };
                *(u16x4*)&Ps[q * 72 + 16 * mtl + 4 * g4] = pk;
            }
        }
        __syncthreads();
        #pragma unroll
        for (int ksl = 0; ksl < 2; ++ksl) {
            bf16x8v a0 = *(const bf16x8v*)&Vs[(l15) * 264 + 64 * kc + 32 * ksl + 8 * g4];
            bf16x8v a1 = *(const bf16x8v*)&Vs[(16 + l15) * 264 + 64 * kc + 32 * ksl + 8 * g4];
            bf16x8v b0 = *(const bf16x8v*)&Ps[(16 * (2 * wv_ + 0) + l15) * 72 + 32 * ksl + 8 * g4];
            bf16x8v b1 = *(const bf16x8v*)&Ps[(16 * (2 * wv_ + 1) + l15) * 72 + 32 * ksl + 8 * g4];
            oacc[0][0] = mfma16(a0, b0, oacc[0][0]); oacc[0][1] = mfma16(a0, b1, oacc[0][1]);
            oacc[1][0] = mfma16(a1, b0, oacc[1][0]); oacc[1][1] = mfma16(a1, b1, oacc[1][1]);
        }
    }

    // epilogue: divide by softmax denom, write out_win[win][c][s]
    #pragma unroll
    for (int mtv = 0; mtv < 2; ++mtv)
        #pragma unroll
        for (int nq = 0; nq < 2; ++nq)
            #pragma unroll
            for (int r = 0; r < 4; ++r) {
                int c = 32 * h + 16 * mtv + 4 * g4 + r;
                int q = 16 * (2 * wv_ + nq) + l15;
                out_win[((long)win * 192 + c) * 256 + q] = oacc[mtv][nq][r] * rden[nq];
            }
}

// ---------------- kernel 3: overlap-add gather + divide by COUNT
__global__ void gather_kernel(const float* __restrict__ out_win, float* __restrict__ out) {
    int idx = blockIdx.x * 256 + threadIdx.x;       // 12,582,912 exact
    int w = idx & 127, hh = (idx >> 7) & 127;
    int v = idx >> 14; int c = v % 192, b = v / 192;
    int khmin = (hh - 2) / 14; if (khmin < 0) khmin = 0;
    int khmax = hh / 14; if (khmax > 8) khmax = 8;
    int kwmin = (w - 2) / 14; if (kwmin < 0) kwmin = 0;
    int kwmax = w / 14; if (kwmax > 8) kwmax = 8;
    float acc = 0.f; int cnt = 0;
    for (int ih = khmin; ih <= khmax; ++ih)
        for (int iw = kwmin; iw <= kwmax; ++iw) {
            int win = b * NWIN + ih * 9 + iw;
            int s = (hh - 14 * ih) * 16 + (w - 14 * iw);
            acc += out_win[((long)win * 192 + c) * 256 + s];
            ++cnt;
        }
    float rc = (cnt == 1) ? 1.0f : (cnt == 2 ? 0.5f : 0.25f);  // cnt in {1,2,4}
    out[idx] = acc * rc;
}

extern "C" void kernel_launch(void* const* d_in, const int* in_sizes, int n_in,
                              void* d_out, int out_size, void* d_ws, size_t ws_size,
                              hipStream_t stream) {
    const float* x     = (const float*)d_in[0];
    const float* Wq    = (const float*)d_in[1];
    const float* Wk    = (const float*)d_in[2];
    const float* Wv    = (const float*)d_in[3];
    const float* gamma = (const float*)d_in[4];
    const float* beta  = (const float*)d_in[5];

    char* ws = (char*)d_ws;
    // ws layout: wbf (221184 B) | q_g (31850496) | k_g (31850496) | vT_g (31850496) | out_win (63700992)
    u16*   wbf     = (u16*)ws;
    u16*   q_g     = (u16*)(ws + 221184);
    u16*   k_g     = (u16*)(ws + 221184 + 31850496L);
    u16*   vT_g    = (u16*)(ws + 221184 + 2 * 31850496L);
    float* out_win = (float*)(ws + 221184 + 3 * 31850496L);

    wconv<<<dim3(432), dim3(256), 0, stream>>>(Wq, Wk, Wv, wbf);
    proj_kernel<<<dim3(BN * 2), dim3(256), 0, stream>>>(x, wbf, gamma, beta, q_g, k_g, vT_g);
    attn_kernel<<<dim3(BN * 6), dim3(512), 0, stream>>>(q_g, k_g, vT_g, out_win);
    gather_kernel<<<dim3(49152), dim3(256), 0, stream>>>(out_win, (float*)d_out);
}

// Round 3
// 218.893 us; speedup vs baseline: 1.2136x; 1.2136x over previous
//
#include <hip/hip_runtime.h>
#include <stdint.h>

#define DEV __device__ __forceinline__

typedef unsigned short u16;
typedef u16   u16x8 __attribute__((ext_vector_type(8)));
typedef u16   u16x4 __attribute__((ext_vector_type(4)));
typedef __bf16 bf16x8v __attribute__((ext_vector_type(8)));
typedef float f32x4 __attribute__((ext_vector_type(4)));

constexpr int NWIN = 81;          // 9x9 windows per batch
constexpr int BN   = 4 * NWIN;    // 324 total windows
constexpr float EPS = 1e-5f;
constexpr float SCALE = 0.07216878364870322f; // 192^-0.5
constexpr int FUSED_SMEM = 160256;            // bytes of dynamic LDS

DEV u16 f2bf(float f) {            // fp32 -> bf16 RNE
    unsigned u = __builtin_bit_cast(unsigned, f);
    u += 0x7fffu + ((u >> 16) & 1u);
    return (u16)(u >> 16);
}

DEV f32x4 mfma16(bf16x8v a, bf16x8v b, f32x4 c) {
    return __builtin_amdgcn_mfma_f32_16x16x32_bf16(a, b, c, 0, 0, 0);
}

// ---------------- kernel 0: convert Wq|Wk|Wv fp32 -> bf16 (contiguous in ws)
__global__ void wconv(const float* __restrict__ wq, const float* __restrict__ wk,
                      const float* __restrict__ wv, u16* __restrict__ dst) {
    int idx = blockIdx.x * 256 + threadIdx.x;       // 3*36864 exact
    const float* src = (idx < 36864) ? wq : (idx < 73728 ? wk : wv);
    int r = (idx < 36864) ? idx : (idx < 73728 ? idx - 36864 : idx - 73728);
    dst[idx] = f2bf(src[r]);
}

// ---------------- kernel 1: per-pixel LN stats (mu, rsqrt(var+eps))
// block = one (b,h) row: 256 threads, float4 loads, 512 blocks.
__global__ void ln_stats(const float* __restrict__ x, float* __restrict__ mu_g,
                         float* __restrict__ rs_g) {
    __shared__ float p1[8][132], p2[8][132];
    const int bh = blockIdx.x;               // 0..511
    const int b = bh >> 7, h = bh & 127;
    const int tid = threadIdx.x;
    const int w4 = tid & 31, cg = tid >> 5;  // 8 channel groups
    const float* base = x + (((long)(b * 192 + cg)) * 128 + h) * 128 + 4 * w4;
    float4 s1 = {0, 0, 0, 0}, s2 = {0, 0, 0, 0};
    #pragma unroll 4
    for (int c = 0; c < 192; c += 8) {       // channel = cg + c
        float4 v = *(const float4*)(base + (long)c * 16384);
        s1.x += v.x; s1.y += v.y; s1.z += v.z; s1.w += v.w;
        s2.x += v.x * v.x; s2.y += v.y * v.y; s2.z += v.z * v.z; s2.w += v.w * v.w;
    }
    *(float4*)&p1[cg][4 * w4] = s1;
    *(float4*)&p2[cg][4 * w4] = s2;
    __syncthreads();
    if (tid < 128) {
        float a = 0.f, q = 0.f;
        #pragma unroll
        for (int g = 0; g < 8; ++g) { a += p1[g][tid]; q += p2[g][tid]; }
        float mu = a * (1.0f / 192.0f);
        float var = q * (1.0f / 192.0f) - mu * mu;
        long pix = ((long)(b * 128) + h) * 128 + tid;
        mu_g[pix] = mu;
        rs_g[pix] = rsqrtf(var + EPS);
    }
}

// ---------------- kernel 2: fused per-window LN-apply + QKV proj + attention
// 324 blocks x 512 threads (8 waves). Dynamic LDS 160,256 B:
//   lx[256][200] bf16 | Qs[256][40] | Ks[256][40] (Ps[256][72] overlays Q+K) | Vs[32][264]
__launch_bounds__(512, 2)
__global__ void fused_kernel(const float* __restrict__ x, const u16* __restrict__ wbf,
                             const float* __restrict__ gamma, const float* __restrict__ beta,
                             const float* __restrict__ mu_g, const float* __restrict__ rs_g,
                             float* __restrict__ out_win) {
    extern __shared__ u16 smem[];
    u16* lx = smem;               // [256][200]
    u16* Qs = smem + 51200;       // [256][40]
    u16* Ks = smem + 61440;       // [256][40]
    u16* Ps = smem + 51200;       // overlay [256][72]
    u16* Vs = smem + 71680;       // [32][264]

    const int tid = threadIdx.x;
    const int win = blockIdx.x;
    const int b = win / NWIN, wi = win % NWIN;
    const int t0 = 14 * (wi / 9), l0 = 14 * (wi % 9);

    // ---- phase 1: load x window once, normalize with precomputed stats -> lx
    {
        const int s = tid & 255, cg = tid >> 8;
        const int dh = s >> 4, dw = s & 15;
        const long pix = ((long)(b * 128) + t0 + dh) * 128 + l0 + dw;
        const float mu = mu_g[pix], rs = rs_g[pix];
        const float* xb = x + (((long)(b * 192 + 96 * cg)) * 128 + t0 + dh) * 128 + l0 + dw;
        #pragma unroll 4
        for (int j = 0; j < 96; ++j) {
            const int c = 96 * cg + j;
            float v = xb[(long)j * 16384];
            lx[s * 200 + c] = f2bf((v - mu) * rs * gamma[c] + beta[c]);
        }
    }

    const int lane = tid & 63, wv_ = tid >> 6;
    const int l15 = lane & 15, g4 = lane >> 4;
    const int ot = wv_ & 1, sg = wv_ >> 1;    // proj: o-tile, s-tile-group

    for (int h = 0; h < 6; ++h) {
        __syncthreads();   // phase-1 done / previous head's LDS reads done

        // ---- per-head proj: Q,K [256][32] and V^T [32][256]
        {
            const u16* wqr = wbf + (32 * h + 16 * ot + l15) * 192;
            const u16* wkr = wqr + 36864;
            const u16* wvr = wqr + 73728;
            bf16x8v bq[6], bk[6], av[6];
            #pragma unroll
            for (int ks = 0; ks < 6; ++ks) {
                bq[ks] = *(const bf16x8v*)&wqr[32 * ks + 8 * g4];
                bk[ks] = *(const bf16x8v*)&wkr[32 * ks + 8 * g4];
                av[ks] = *(const bf16x8v*)&wvr[32 * ks + 8 * g4];
            }
            #pragma unroll
            for (int i = 0; i < 4; ++i) {
                const int st = 4 * sg + i;
                f32x4 aq = {}, ak = {}, avv = {};
                #pragma unroll
                for (int ks = 0; ks < 6; ++ks) {
                    bf16x8v a = *(const bf16x8v*)&lx[(16 * st + l15) * 200 + 32 * ks + 8 * g4];
                    aq  = mfma16(a, bq[ks], aq);     // D: row=s, col=o
                    ak  = mfma16(a, bk[ks], ak);
                    avv = mfma16(av[ks], a, avv);    // D: row=o, col=s
                }
                #pragma unroll
                for (int r = 0; r < 4; ++r) {
                    Qs[(16 * st + 4 * g4 + r) * 40 + 16 * ot + l15] = f2bf(aq[r]);
                    Ks[(16 * st + 4 * g4 + r) * 40 + 16 * ot + l15] = f2bf(ak[r]);
                    Vs[(16 * ot + 4 * g4 + r) * 264 + 16 * st + l15] = f2bf(avv[r]);
                }
            }
        }
        __syncthreads();

        // ---- scoresT[key][q] = K . Q^T ; wave owns q-tiles {2wv_, 2wv_+1}
        f32x4 sc[16][2];
        {
            bf16x8v bq0 = *(const bf16x8v*)&Qs[(16 * (2 * wv_ + 0) + l15) * 40 + 8 * g4];
            bf16x8v bq1 = *(const bf16x8v*)&Qs[(16 * (2 * wv_ + 1) + l15) * 40 + 8 * g4];
            const f32x4 z = {0.f, 0.f, 0.f, 0.f};
            #pragma unroll
            for (int mt = 0; mt < 16; ++mt) {
                bf16x8v a = *(const bf16x8v*)&Ks[(16 * mt + l15) * 40 + 8 * g4];
                sc[mt][0] = mfma16(a, bq0, z);
                sc[mt][1] = mfma16(a, bq1, z);
            }
        }

        // ---- softmax over keys: lane-local 64 vals + xor16 + xor32
        float rden[2];
        #pragma unroll
        for (int nq = 0; nq < 2; ++nq) {
            float mx = -1e30f;
            #pragma unroll
            for (int mt = 0; mt < 16; ++mt)
                #pragma unroll
                for (int r = 0; r < 4; ++r) mx = fmaxf(mx, sc[mt][nq][r]);
            mx = fmaxf(mx, __shfl_xor(mx, 16, 64));
            mx = fmaxf(mx, __shfl_xor(mx, 32, 64));
            float sum = 0.f;
            #pragma unroll
            for (int mt = 0; mt < 16; ++mt)
                #pragma unroll
                for (int r = 0; r < 4; ++r) {
                    float p = __expf((sc[mt][nq][r] - mx) * SCALE);
                    sc[mt][nq][r] = p; sum += p;
                }
            sum += __shfl_xor(sum, 16, 64);
            sum += __shfl_xor(sum, 32, 64);
            rden[nq] = 1.0f / sum;
        }

        // ---- PV: outT[dv][q] += V^T . P^T, P staged per 64-key chunk (Ps overlays Q/K)
        f32x4 oacc[2][2] = {};
        #pragma unroll
        for (int kc = 0; kc < 4; ++kc) {
            __syncthreads();   // prior readers of Ps region (or Q/K reads at kc=0) done
            #pragma unroll
            for (int mtl = 0; mtl < 4; ++mtl) {
                int mt = 4 * kc + mtl;
                #pragma unroll
                for (int nq = 0; nq < 2; ++nq) {
                    int q = 16 * (2 * wv_ + nq) + l15;
                    u16x4 pk = { f2bf(sc[mt][nq][0]), f2bf(sc[mt][nq][1]),
                                 f2bf(sc[mt][nq][2]), f2bf(sc[mt][nq][3]) };
                    *(u16x4*)&Ps[q * 72 + 16 * mtl + 4 * g4] = pk;
                }
            }
            __syncthreads();
            #pragma unroll
            for (int ksl = 0; ksl < 2; ++ksl) {
                bf16x8v a0 = *(const bf16x8v*)&Vs[(l15) * 264 + 64 * kc + 32 * ksl + 8 * g4];
                bf16x8v a1 = *(const bf16x8v*)&Vs[(16 + l15) * 264 + 64 * kc + 32 * ksl + 8 * g4];
                bf16x8v b0 = *(const bf16x8v*)&Ps[(16 * (2 * wv_ + 0) + l15) * 72 + 32 * ksl + 8 * g4];
                bf16x8v b1 = *(const bf16x8v*)&Ps[(16 * (2 * wv_ + 1) + l15) * 72 + 32 * ksl + 8 * g4];
                oacc[0][0] = mfma16(a0, b0, oacc[0][0]); oacc[0][1] = mfma16(a0, b1, oacc[0][1]);
                oacc[1][0] = mfma16(a1, b0, oacc[1][0]); oacc[1][1] = mfma16(a1, b1, oacc[1][1]);
            }
        }

        // ---- epilogue: divide by denom, write out_win[win][c][s]
        #pragma unroll
        for (int mtv = 0; mtv < 2; ++mtv)
            #pragma unroll
            for (int nq = 0; nq < 2; ++nq)
                #pragma unroll
                for (int r = 0; r < 4; ++r) {
                    int c = 32 * h + 16 * mtv + 4 * g4 + r;
                    int q = 16 * (2 * wv_ + nq) + l15;
                    out_win[((long)win * 192 + c) * 256 + q] = oacc[mtv][nq][r] * rden[nq];
                }
    }
}

// ---------------- kernel 3: overlap-add gather + divide by COUNT
__global__ void gather_kernel(const float* __restrict__ out_win, float* __restrict__ out) {
    int idx = blockIdx.x * 256 + threadIdx.x;       // 12,582,912 exact
    int w = idx & 127, hh = (idx >> 7) & 127;
    int v = idx >> 14; int c = v % 192, b = v / 192;
    int khmin = (hh - 2) / 14; if (khmin < 0) khmin = 0;
    int khmax = hh / 14; if (khmax > 8) khmax = 8;
    int kwmin = (w - 2) / 14; if (kwmin < 0) kwmin = 0;
    int kwmax = w / 14; if (kwmax > 8) kwmax = 8;
    float acc = 0.f; int cnt = 0;
    for (int ih = khmin; ih <= khmax; ++ih)
        for (int iw = kwmin; iw <= kwmax; ++iw) {
            int win = b * NWIN + ih * 9 + iw;
            int s = (hh - 14 * ih) * 16 + (w - 14 * iw);
            acc += out_win[((long)win * 192 + c) * 256 + s];
            ++cnt;
        }
    float rc = (cnt == 1) ? 1.0f : (cnt == 2 ? 0.5f : 0.25f);  // cnt in {1,2,4}
    out[idx] = acc * rc;
}

extern "C" void kernel_launch(void* const* d_in, const int* in_sizes, int n_in,
                              void* d_out, int out_size, void* d_ws, size_t ws_size,
                              hipStream_t stream) {
    const float* x     = (const float*)d_in[0];
    const float* Wq    = (const float*)d_in[1];
    const float* Wk    = (const float*)d_in[2];
    const float* Wv    = (const float*)d_in[3];
    const float* gamma = (const float*)d_in[4];
    const float* beta  = (const float*)d_in[5];

    char* ws = (char*)d_ws;
    // ws layout: wbf (221184) | mu_g (262144) | rs_g (262144) | out_win (63700992)
    u16*   wbf     = (u16*)ws;
    float* mu_g    = (float*)(ws + 221184);
    float* rs_g    = (float*)(ws + 221184 + 262144);
    float* out_win = (float*)(ws + 221184 + 2 * 262144);

    (void)hipFuncSetAttribute((const void*)fused_kernel,
                              hipFuncAttributeMaxDynamicSharedMemorySize, FUSED_SMEM);

    wconv<<<dim3(432), dim3(256), 0, stream>>>(Wq, Wk, Wv, wbf);
    ln_stats<<<dim3(512), dim3(256), 0, stream>>>(x, mu_g, rs_g);
    fused_kernel<<<dim3(BN), dim3(512), FUSED_SMEM, stream>>>(x, wbf, gamma, beta, mu_g, rs_g, out_win);
    gather_kernel<<<dim3(49152), dim3(256), 0, stream>>>(out_win, (float*)d_out);
}